// Round 13
// baseline (410.370 us; speedup 1.0000x reference)
//
#include <hip/hip_runtime.h>
#include <math.h>

#define NN 100000
#define NE 1200000
#define EPSV 1e-5f

// binning geometry
#define BUCKET_BITS 8
#define BNODES 256                               // nodes per bucket
#define NBUCK ((NN + BNODES - 1) / BNODES)       // 391
#define NCHUNKS 256
#define CHUNK ((NE + NCHUNKS - 1) / NCHUNKS)     // 4688
#define SCAN_N (NBUCK * NCHUNKS)                 // 100096
#define BUFCAP 4096                              // max edges per bucket (mean 3072)
#define TILE_SHIFT 14                            // src tile = src >> 14 (7 tiles)
#define NKEY 2048                                // 256 dst_local x 8 tiles

typedef __attribute__((ext_vector_type(8))) short short8;
typedef __attribute__((ext_vector_type(4))) float f32x4;

__device__ __forceinline__ unsigned short f2bf(float f) {
    unsigned int u = __float_as_uint(f);
    u += 0x7FFF + ((u >> 16) & 1);               // round-to-nearest-even
    return (unsigned short)(u >> 16);
}
__device__ __forceinline__ float bf2f(unsigned short u) {
    return __uint_as_float(((unsigned int)u) << 16);
}

// ---------------- MFMA GEMM: Y[n x DOUT](bf16) = X[n x DIN] @ W[DIN x DOUT](fp32) ----------------
// 256 threads = 4 waves; 64 rows/block; wave w owns rows w*16..+15, all DOUT cols.
// BNRELU: scale/shift recomputed per block from stats[128]+g+beta.
// BF16IN: X rows are bf16 (agg output); else fp32.
template<int DIN, int DOUT, int NF, bool BNRELU, bool BF16IN>
__global__ __launch_bounds__(256)
void gemm_mfma_kernel(const void* __restrict__ Xv, const float* __restrict__ W,
                      unsigned short* __restrict__ Y, int n,
                      const float* __restrict__ stats, const float* __restrict__ g,
                      const float* __restrict__ beta) {
    constexpr int LD = DIN + 8;                  // bf16 units
    constexpr int DP = NF * 16;                  // padded col count
    static_assert(DIN % 32 == 0, "K multiple of 32");
    __shared__ unsigned short Xs[64][LD];
    __shared__ unsigned short Wt[DP][LD];
    __shared__ float sc_s[64], sh_s[64];

    const int tid = threadIdx.x;
    const int row0 = blockIdx.x * 64;

    if (BNRELU) {
        if (tid < 64) {
            float mu = stats[tid] * (1.f / NN);
            float var = stats[64 + tid] * (1.f / NN) - mu * mu;
            float rs = rsqrtf(var + EPSV);
            float sc = g[tid] * rs;
            sc_s[tid] = sc;
            sh_s[tid] = beta[tid] - mu * sc;
        }
        __syncthreads();
    }

    // ---- stage X tile -> bf16 (optionally BN+ReLU) ----
    for (int i = tid; i < 64 * (DIN / 4); i += 256) {
        int r = i / (DIN / 4);
        int c4 = i % (DIN / 4);
        int gr = row0 + r;
        float v0 = 0.f, v1 = 0.f, v2 = 0.f, v3 = 0.f;
        if (gr < n) {
            if (BF16IN) {
                const unsigned short* Xb = (const unsigned short*)Xv;
                ushort4 u = *(const ushort4*)&Xb[(size_t)gr * DIN + c4 * 4];
                v0 = bf2f(u.x); v1 = bf2f(u.y); v2 = bf2f(u.z); v3 = bf2f(u.w);
            } else {
                const float* Xf = (const float*)Xv;
                float4 f = *(const float4*)&Xf[(size_t)gr * DIN + c4 * 4];
                v0 = f.x; v1 = f.y; v2 = f.z; v3 = f.w;
            }
        }
        if (BNRELU) {
            int c = c4 * 4;
            v0 = fmaxf(v0 * sc_s[c + 0] + sh_s[c + 0], 0.f);
            v1 = fmaxf(v1 * sc_s[c + 1] + sh_s[c + 1], 0.f);
            v2 = fmaxf(v2 * sc_s[c + 2] + sh_s[c + 2], 0.f);
            v3 = fmaxf(v3 * sc_s[c + 3] + sh_s[c + 3], 0.f);
        }
        ushort4 o;
        o.x = f2bf(v0); o.y = f2bf(v1); o.z = f2bf(v2); o.w = f2bf(v3);
        *(ushort4*)&Xs[r][c4 * 4] = o;
    }
    // ---- stage W transposed (fp32 -> bf16), zero-pad cols >= DOUT ----
    for (int i = tid; i < DIN * DOUT; i += 256) {
        int k = i / DOUT;
        int c = i - k * DOUT;
        Wt[c][k] = f2bf(W[i]);
    }
    if (DP > DOUT) {
        for (int i = tid; i < DIN * (DP - DOUT); i += 256) {
            int k = i / (DP - DOUT);
            int c = DOUT + (i - k * (DP - DOUT));
            Wt[c][k] = 0;
        }
    }
    __syncthreads();

    const int w = tid >> 6;
    const int lane = tid & 63;
    const int lr = lane & 15;
    const int kg = lane >> 4;

    f32x4 acc[NF];
#pragma unroll
    for (int nf = 0; nf < NF; ++nf) acc[nf] = (f32x4){0.f, 0.f, 0.f, 0.f};

#pragma unroll
    for (int t = 0; t < DIN / 32; ++t) {
        const int kb = t * 32 + kg * 8;
        short8 a = *(const short8*)&Xs[w * 16 + lr][kb];
#pragma unroll
        for (int nf = 0; nf < NF; ++nf) {
            short8 b = *(const short8*)&Wt[nf * 16 + lr][kb];
            acc[nf] = __builtin_amdgcn_mfma_f32_16x16x32_bf16(a, b, acc[nf], 0, 0, 0);
        }
    }

    // ---- C write: row=(kg*4+j), col=nf*16+lr ----
#pragma unroll
    for (int nf = 0; nf < NF; ++nf) {
        const int c = nf * 16 + lr;
        if (c < DOUT) {
#pragma unroll
            for (int j = 0; j < 4; ++j) {
                int gr = row0 + w * 16 + kg * 4 + j;
                if (gr < n)
                    Y[(size_t)gr * DOUT + c] = f2bf(acc[nf][j]);
            }
        }
    }
}

// ---------------- Pass 1: per-chunk bucket histogram ----------------
__global__ __launch_bounds__(256)
void hist_kernel(const int* __restrict__ dst, int* __restrict__ counts) {
    __shared__ int cnt[NBUCK];
    for (int i = threadIdx.x; i < NBUCK; i += 256) cnt[i] = 0;
    __syncthreads();
    const int base = blockIdx.x * CHUNK;
    const int end = min(base + CHUNK, NE);
    for (int e = base + threadIdx.x; e < end; e += 256)
        atomicAdd(&cnt[dst[e] >> BUCKET_BITS], 1);
    __syncthreads();
    for (int b = threadIdx.x; b < NBUCK; b += 256)
        counts[b * NCHUNKS + blockIdx.x] = cnt[b];
}

// ---------------- Fused single-block exclusive scan (also zeros stats banks) ----------------
__global__ __launch_bounds__(1024)
void scan_fused_kernel(const int* __restrict__ v, int* __restrict__ out, int n,
                       float* __restrict__ stats) {
    __shared__ int ps[1024];
    const int tid = threadIdx.x;
    if (tid < 256) stats[tid] = 0.f;             // zero stats1+stats2 (2x128)
    const int per = (n + 1023) / 1024;
    const int b = tid * per;
    const int e = min(b + per, n);
    int sum = 0;
    for (int i = b; i < e; ++i) sum += v[i];
    ps[tid] = sum;
    __syncthreads();
    for (int d = 1; d < 1024; d <<= 1) {
        int t = (tid >= d) ? ps[tid - d] : 0;
        __syncthreads();
        ps[tid] += t;
        __syncthreads();
    }
    int run = ps[tid] - sum;                     // exclusive base for this thread's range
    for (int i = b; i < e; ++i) { int c = v[i]; out[i] = run; run += c; }
}

// ---------------- Pass 2: place edges into (bucket,chunk) runs ----------------
// payload: .x = src | (dst_local << 17) as bits, .y = weight
__global__ __launch_bounds__(256)
void place_kernel(const int* __restrict__ src, const int* __restrict__ dst,
                  const float* __restrict__ ew, const int* __restrict__ gofs,
                  float2* __restrict__ binned) {
    __shared__ int lcur[NBUCK];
    for (int i = threadIdx.x; i < NBUCK; i += 256) lcur[i] = 0;
    __syncthreads();
    const int base = blockIdx.x * CHUNK;
    const int end = min(base + CHUNK, NE);
    for (int e = base + threadIdx.x; e < end; e += 256) {
        int d = dst[e];
        int b = d >> BUCKET_BITS;
        int p = gofs[b * NCHUNKS + blockIdx.x] + atomicAdd(&lcur[b], 1);
        float2 pk;
        pk.x = __int_as_float(src[e] | ((d & (BNODES - 1)) << 17));
        pk.y = ew[e];
        binned[p] = pk;
    }
}

// ---------------- Pass 3: per-bucket LDS counting sort by (dst_local, src_tile) ----------------
__global__ __launch_bounds__(256)
void bucket_sort_kernel(const float2* __restrict__ binned, const int* __restrict__ gofs,
                        float2* __restrict__ edges, int* __restrict__ off) {
    __shared__ float2 buf[BUFCAP];
    __shared__ int pos[NKEY];
    __shared__ int psum[256];
    const int tid = threadIdx.x;
    const int b = blockIdx.x;
    const int s = gofs[b * NCHUNKS];
    const int e = (b == NBUCK - 1) ? NE : gofs[(b + 1) * NCHUNKS];
    const int n = e - s;

    for (int i = tid; i < NKEY; i += 256) pos[i] = 0;
    __syncthreads();
    for (int i = tid; i < n; i += 256) {
        int v = __float_as_int(binned[s + i].x);
        int dl = (v >> 17) & (BNODES - 1);
        int t = (v & 0x1FFFF) >> TILE_SHIFT;
        atomicAdd(&pos[(dl << 3) | t], 1);
    }
    __syncthreads();
    // exclusive scan of pos[NKEY]: NKEY/256 sequential per thread + 256-scan
    constexpr int PER = NKEY / 256;              // 8
    const int base = tid * PER;
    int run = 0;
#pragma unroll
    for (int i = 0; i < PER; ++i) { int c = pos[base + i]; pos[base + i] = run; run += c; }
    psum[tid] = run;
    __syncthreads();
    for (int d = 1; d < 256; d <<= 1) {
        int t = (tid >= d) ? psum[tid - d] : 0;
        __syncthreads();
        psum[tid] += t;
        __syncthreads();
    }
    const int chunk_off = psum[tid] - run;
#pragma unroll
    for (int i = 0; i < PER; ++i) pos[base + i] += chunk_off;
    __syncthreads();
    // node offsets = first key of each dst_local (before pos is consumed as cursor)
    const int node0 = b * BNODES;
    if (tid < BNODES) {
        int node = node0 + tid;
        if (node < NN) off[node] = s + pos[tid << 3];
    }
    if (b == NBUCK - 1 && tid == 0) off[NN] = NE;
    __syncthreads();
    // scatter into LDS by key
    for (int i = tid; i < n; i += 256) {
        float2 pk = binned[s + i];
        int v = __float_as_int(pk.x);
        int dl = (v >> 17) & (BNODES - 1);
        int t = (v & 0x1FFFF) >> TILE_SHIFT;
        int p = atomicAdd(&pos[(dl << 3) | t], 1);
        pk.x = __int_as_float(v & 0x1FFFF);      // strip dst_local
        if (p < BUFCAP) buf[p] = pk;
    }
    __syncthreads();
    const int m = (n < BUFCAP) ? n : BUFCAP;
    for (int i = tid; i < m; i += 256)
        edges[s + i] = buf[i];
}

// ---------------- Aggregation (free-running, no barriers) ----------------
// One node per 32-lane half-wave; 8 nodes per 256-thread block.
// BF16OUT: pack 2 features into one uint store; else fp32 float2 (+bias).
template<int D, bool BIAS, bool BF16OUT>
__global__ __launch_bounds__(256)
void agg_kernel(const unsigned short* __restrict__ h, const float2* __restrict__ edges,
                const int* __restrict__ off, unsigned int* __restrict__ y16,
                float* __restrict__ yf, const float* __restrict__ bias) {
    constexpr int NU = D / 2;
    const unsigned int* __restrict__ h32 = (const unsigned int*)h;
    const int fl = threadIdx.x & 31;
    const int v = blockIdx.x * 8 + (threadIdx.x >> 5);
    if (v >= NN) return;
    if (fl >= NU) return;
    const int s = off[v], e = off[v + 1];
    float a0 = 0.f, a1 = 0.f, b0 = 0.f, b1 = 0.f;
    float c0 = 0.f, c1 = 0.f, d0 = 0.f, d1 = 0.f;
    int j = s;
    for (; j + 7 < e; j += 8) {
        float2 p0 = edges[j + 0], p1 = edges[j + 1], p2 = edges[j + 2], p3 = edges[j + 3];
        float2 p4 = edges[j + 4], p5 = edges[j + 5], p6 = edges[j + 6], p7 = edges[j + 7];
        unsigned int h0 = h32[(size_t)__float_as_int(p0.x) * NU + fl];
        unsigned int h1 = h32[(size_t)__float_as_int(p1.x) * NU + fl];
        unsigned int h2 = h32[(size_t)__float_as_int(p2.x) * NU + fl];
        unsigned int h3 = h32[(size_t)__float_as_int(p3.x) * NU + fl];
        unsigned int h4 = h32[(size_t)__float_as_int(p4.x) * NU + fl];
        unsigned int h5 = h32[(size_t)__float_as_int(p5.x) * NU + fl];
        unsigned int h6 = h32[(size_t)__float_as_int(p6.x) * NU + fl];
        unsigned int h7 = h32[(size_t)__float_as_int(p7.x) * NU + fl];
        a0 += bf2f((unsigned short)h0) * p0.y + bf2f((unsigned short)h1) * p1.y;
        a1 += bf2f((unsigned short)(h0 >> 16)) * p0.y + bf2f((unsigned short)(h1 >> 16)) * p1.y;
        b0 += bf2f((unsigned short)h2) * p2.y + bf2f((unsigned short)h3) * p3.y;
        b1 += bf2f((unsigned short)(h2 >> 16)) * p2.y + bf2f((unsigned short)(h3 >> 16)) * p3.y;
        c0 += bf2f((unsigned short)h4) * p4.y + bf2f((unsigned short)h5) * p5.y;
        c1 += bf2f((unsigned short)(h4 >> 16)) * p4.y + bf2f((unsigned short)(h5 >> 16)) * p5.y;
        d0 += bf2f((unsigned short)h6) * p6.y + bf2f((unsigned short)h7) * p7.y;
        d1 += bf2f((unsigned short)(h6 >> 16)) * p6.y + bf2f((unsigned short)(h7 >> 16)) * p7.y;
    }
    for (; j + 3 < e; j += 4) {
        float2 p0 = edges[j + 0], p1 = edges[j + 1], p2 = edges[j + 2], p3 = edges[j + 3];
        unsigned int h0 = h32[(size_t)__float_as_int(p0.x) * NU + fl];
        unsigned int h1 = h32[(size_t)__float_as_int(p1.x) * NU + fl];
        unsigned int h2 = h32[(size_t)__float_as_int(p2.x) * NU + fl];
        unsigned int h3 = h32[(size_t)__float_as_int(p3.x) * NU + fl];
        a0 += bf2f((unsigned short)h0) * p0.y + bf2f((unsigned short)h1) * p1.y;
        a1 += bf2f((unsigned short)(h0 >> 16)) * p0.y + bf2f((unsigned short)(h1 >> 16)) * p1.y;
        b0 += bf2f((unsigned short)h2) * p2.y + bf2f((unsigned short)h3) * p3.y;
        b1 += bf2f((unsigned short)(h2 >> 16)) * p2.y + bf2f((unsigned short)(h3 >> 16)) * p3.y;
    }
    for (; j < e; ++j) {
        float2 p0 = edges[j];
        unsigned int h0 = h32[(size_t)__float_as_int(p0.x) * NU + fl];
        c0 += bf2f((unsigned short)h0) * p0.y;
        c1 += bf2f((unsigned short)(h0 >> 16)) * p0.y;
    }
    float r0 = (a0 + b0) + (c0 + d0);
    float r1 = (a1 + b1) + (c1 + d1);
    if (BIAS) { r0 += bias[2 * fl]; r1 += bias[2 * fl + 1]; }
    if (BF16OUT) {
        unsigned int pk = (unsigned int)f2bf(r0) | ((unsigned int)f2bf(r1) << 16);
        y16[(size_t)v * NU + fl] = pk;
    } else {
        *(float2*)&yf[(size_t)v * D + 2 * fl] = make_float2(r0, r1);
    }
}

// ---------------- BN stats over bf16 rows: stats[0..63]=sum, stats[64..127]=sumsq ----------------
__global__ __launch_bounds__(256)
void bn_stats_bf16_kernel(const unsigned int* __restrict__ x32, float* __restrict__ stats, int n) {
    __shared__ float s0[256], s1[256], q0[256], q1[256];
    const int tid = threadIdx.x;
    const int fl = tid & 31;
    const int rg = tid >> 5;
    float sum0 = 0.f, sum1 = 0.f, sq0 = 0.f, sq1 = 0.f;
    for (int r = blockIdx.x * 8 + rg; r < n; r += gridDim.x * 8) {
        unsigned int u = x32[(size_t)r * 32 + fl];
        float v0 = bf2f((unsigned short)u);
        float v1 = bf2f((unsigned short)(u >> 16));
        sum0 += v0; sum1 += v1;
        sq0 += v0 * v0; sq1 += v1 * v1;
    }
    s0[tid] = sum0; s1[tid] = sum1; q0[tid] = sq0; q1[tid] = sq1;
    __syncthreads();
    if (tid < 32) {
        float ts0 = 0.f, ts1 = 0.f, tq0 = 0.f, tq1 = 0.f;
#pragma unroll
        for (int k = 0; k < 8; ++k) {
            ts0 += s0[tid + 32 * k]; ts1 += s1[tid + 32 * k];
            tq0 += q0[tid + 32 * k]; tq1 += q1[tid + 32 * k];
        }
        atomicAdd(&stats[2 * tid], ts0);
        atomicAdd(&stats[2 * tid + 1], ts1);
        atomicAdd(&stats[64 + 2 * tid], tq0);
        atomicAdd(&stats[64 + 2 * tid + 1], tq1);
    }
}

extern "C" void kernel_launch(void* const* d_in, const int* in_sizes, int n_in,
                              void* d_out, int out_size, void* d_ws, size_t ws_size,
                              hipStream_t stream) {
    const float* nf    = (const float*)d_in[0];
    const int*   ei    = (const int*)d_in[1];   // [2][E]
    const float* ew    = (const float*)d_in[2];
    const float* W1    = (const float*)d_in[3];
    // b1 (d_in[4]) cancels inside BN
    const float* g1    = (const float*)d_in[5];
    const float* beta1 = (const float*)d_in[6];
    const float* W2    = (const float*)d_in[7];
    // b2 (d_in[8]) cancels inside BN
    const float* g2    = (const float*)d_in[9];
    const float* beta2 = (const float*)d_in[10];
    const float* W3    = (const float*)d_in[11];
    const float* b3    = (const float*)d_in[12];

    const int* src = ei;
    const int* dst = ei + NE;

    // workspace layout (4B units)
    unsigned short* hbuf = (unsigned short*)d_ws;        // NN*64 bf16 (12.8MB); binned aliases it
    unsigned short* abuf = hbuf + (size_t)NN * 64;       // NN*64 bf16 (agg output)
    float2* edges  = (float2*)(abuf + (size_t)NN * 64);  // NE float2
    int*    off    = (int*)(edges + NE);                 // NN+1
    int*    counts = off + NN + 1;                       // SCAN_N
    int*    gofs   = counts + SCAN_N;                    // SCAN_N
    float*  stats1 = (float*)(gofs + SCAN_N);            // 128
    float*  stats2 = stats1 + 128;                       // 128

    float2* binned = (float2*)hbuf;                      // scratch, consumed before gemm1

    float* out = (float*)d_out;

    const int ggrid = (NN + 63) / 64;      // 1563
    const int agrid = (NN + 7) / 8;        // 12500

    // ---------- CSR build: hist -> fused scan (also zeros stats) -> place -> bucket sort ----------
    hist_kernel<<<NCHUNKS, 256, 0, stream>>>(dst, counts);
    scan_fused_kernel<<<1, 1024, 0, stream>>>(counts, gofs, SCAN_N, stats1);
    place_kernel<<<NCHUNKS, 256, 0, stream>>>(src, dst, ew, gofs, binned);
    bucket_sort_kernel<<<NBUCK, 256, 0, stream>>>(binned, gofs, edges, off);

    // ---------- layer 1: GCNConv(128->64); agg -> bf16; stats1 ----------
    gemm_mfma_kernel<128, 64, 4, false, false><<<ggrid, 256, 0, stream>>>(
        nf, W1, hbuf, NN, nullptr, nullptr, nullptr);
    agg_kernel<64, false, true><<<agrid, 256, 0, stream>>>(
        hbuf, edges, off, (unsigned int*)abuf, nullptr, nullptr);
    bn_stats_bf16_kernel<<<512, 256, 0, stream>>>((const unsigned int*)abuf, stats1, NN);

    // ---------- layer 2: BN1+ReLU fused in GEMM; agg -> bf16; stats2 ----------
    gemm_mfma_kernel<64, 64, 4, true, true><<<ggrid, 256, 0, stream>>>(
        abuf, W2, hbuf, NN, stats1, g1, beta1);
    agg_kernel<64, false, true><<<agrid, 256, 0, stream>>>(
        hbuf, edges, off, (unsigned int*)abuf, nullptr, nullptr);
    bn_stats_bf16_kernel<<<512, 256, 0, stream>>>((const unsigned int*)abuf, stats2, NN);

    // ---------- layer 3: BN2+ReLU fused in GEMM; agg + b3 -> out (fp32) ----------
    gemm_mfma_kernel<64, 40, 3, true, true><<<ggrid, 256, 0, stream>>>(
        abuf, W3, hbuf, NN, stats2, g2, beta2);
    agg_kernel<40, true, false><<<agrid, 256, 0, stream>>>(
        hbuf, edges, off, nullptr, out, b3);
}

// Round 14
// 263.107 us; speedup vs baseline: 1.5597x; 1.5597x over previous
//
#include <hip/hip_runtime.h>
#include <math.h>

#define NN 100000
#define NE 1200000
#define EPSV 1e-5f

// binning geometry
#define BUCKET_BITS 8
#define BNODES 256                               // nodes per bucket
#define NBUCK ((NN + BNODES - 1) / BNODES)       // 391
#define NCHUNKS 256
#define CHUNK ((NE + NCHUNKS - 1) / NCHUNKS)     // 4688
#define SCAN_N (NBUCK * NCHUNKS)                 // 100096
#define BUFCAP 4096                              // max edges per bucket (mean 3072)
#define TILE_SHIFT 14                            // src tile = src >> 14
#define NKEY 2048                                // 256 dst_local x 8 tiles

typedef __attribute__((ext_vector_type(8))) short short8;
typedef __attribute__((ext_vector_type(4))) float f32x4;

__device__ __forceinline__ unsigned short f2bf(float f) {
    unsigned int u = __float_as_uint(f);
    u += 0x7FFF + ((u >> 16) & 1);               // round-to-nearest-even
    return (unsigned short)(u >> 16);
}
__device__ __forceinline__ float bf2f(unsigned short u) {
    return __uint_as_float(((unsigned int)u) << 16);
}

// ---------------- MFMA GEMM: Y[n x DOUT](bf16) = X[n x DIN] @ W[DIN x DOUT](fp32) ----------------
// 256 threads = 4 waves; 64 rows/block; wave w owns rows w*16..+15, all DOUT cols.
// BNRELU: scale/shift recomputed per block from stats[128]+g+beta.
// BF16IN: X rows are bf16 (agg output); else fp32.
template<int DIN, int DOUT, int NF, bool BNRELU, bool BF16IN>
__global__ __launch_bounds__(256)
void gemm_mfma_kernel(const void* __restrict__ Xv, const float* __restrict__ W,
                      unsigned short* __restrict__ Y, int n,
                      const float* __restrict__ stats, const float* __restrict__ g,
                      const float* __restrict__ beta) {
    constexpr int LD = DIN + 8;                  // bf16 units
    constexpr int DP = NF * 16;                  // padded col count
    static_assert(DIN % 32 == 0, "K multiple of 32");
    __shared__ unsigned short Xs[64][LD];
    __shared__ unsigned short Wt[DP][LD];
    __shared__ float sc_s[64], sh_s[64];

    const int tid = threadIdx.x;
    const int row0 = blockIdx.x * 64;

    if (BNRELU) {
        if (tid < 64) {
            float mu = stats[tid] * (1.f / NN);
            float var = stats[64 + tid] * (1.f / NN) - mu * mu;
            float rs = rsqrtf(var + EPSV);
            float sc = g[tid] * rs;
            sc_s[tid] = sc;
            sh_s[tid] = beta[tid] - mu * sc;
        }
        __syncthreads();
    }

    // ---- stage X tile -> bf16 (optionally BN+ReLU) ----
    for (int i = tid; i < 64 * (DIN / 4); i += 256) {
        int r = i / (DIN / 4);
        int c4 = i % (DIN / 4);
        int gr = row0 + r;
        float v0 = 0.f, v1 = 0.f, v2 = 0.f, v3 = 0.f;
        if (gr < n) {
            if (BF16IN) {
                const unsigned short* Xb = (const unsigned short*)Xv;
                ushort4 u = *(const ushort4*)&Xb[(size_t)gr * DIN + c4 * 4];
                v0 = bf2f(u.x); v1 = bf2f(u.y); v2 = bf2f(u.z); v3 = bf2f(u.w);
            } else {
                const float* Xf = (const float*)Xv;
                float4 f = *(const float4*)&Xf[(size_t)gr * DIN + c4 * 4];
                v0 = f.x; v1 = f.y; v2 = f.z; v3 = f.w;
            }
        }
        if (BNRELU) {
            int c = c4 * 4;
            v0 = fmaxf(v0 * sc_s[c + 0] + sh_s[c + 0], 0.f);
            v1 = fmaxf(v1 * sc_s[c + 1] + sh_s[c + 1], 0.f);
            v2 = fmaxf(v2 * sc_s[c + 2] + sh_s[c + 2], 0.f);
            v3 = fmaxf(v3 * sc_s[c + 3] + sh_s[c + 3], 0.f);
        }
        ushort4 o;
        o.x = f2bf(v0); o.y = f2bf(v1); o.z = f2bf(v2); o.w = f2bf(v3);
        *(ushort4*)&Xs[r][c4 * 4] = o;
    }
    // ---- stage W transposed (fp32 -> bf16), zero-pad cols >= DOUT ----
    for (int i = tid; i < DIN * DOUT; i += 256) {
        int k = i / DOUT;
        int c = i - k * DOUT;
        Wt[c][k] = f2bf(W[i]);
    }
    if (DP > DOUT) {
        for (int i = tid; i < DIN * (DP - DOUT); i += 256) {
            int k = i / (DP - DOUT);
            int c = DOUT + (i - k * (DP - DOUT));
            Wt[c][k] = 0;
        }
    }
    __syncthreads();

    const int w = tid >> 6;
    const int lane = tid & 63;
    const int lr = lane & 15;
    const int kg = lane >> 4;

    f32x4 acc[NF];
#pragma unroll
    for (int nf = 0; nf < NF; ++nf) acc[nf] = (f32x4){0.f, 0.f, 0.f, 0.f};

#pragma unroll
    for (int t = 0; t < DIN / 32; ++t) {
        const int kb = t * 32 + kg * 8;
        short8 a = *(const short8*)&Xs[w * 16 + lr][kb];
#pragma unroll
        for (int nf = 0; nf < NF; ++nf) {
            short8 b = *(const short8*)&Wt[nf * 16 + lr][kb];
            acc[nf] = __builtin_amdgcn_mfma_f32_16x16x32_bf16(a, b, acc[nf], 0, 0, 0);
        }
    }

    // ---- C write: row=(kg*4+j), col=nf*16+lr ----
#pragma unroll
    for (int nf = 0; nf < NF; ++nf) {
        const int c = nf * 16 + lr;
        if (c < DOUT) {
#pragma unroll
            for (int j = 0; j < 4; ++j) {
                int gr = row0 + w * 16 + kg * 4 + j;
                if (gr < n)
                    Y[(size_t)gr * DOUT + c] = f2bf(acc[nf][j]);
            }
        }
    }
}

// ---------------- Pass 1: per-chunk bucket histogram ----------------
__global__ __launch_bounds__(256)
void hist_kernel(const int* __restrict__ dst, int* __restrict__ counts) {
    __shared__ int cnt[NBUCK];
    for (int i = threadIdx.x; i < NBUCK; i += 256) cnt[i] = 0;
    __syncthreads();
    const int base = blockIdx.x * CHUNK;
    const int end = min(base + CHUNK, NE);
    for (int e = base + threadIdx.x; e < end; e += 256)
        atomicAdd(&cnt[dst[e] >> BUCKET_BITS], 1);
    __syncthreads();
    for (int b = threadIdx.x; b < NBUCK; b += 256)
        counts[b * NCHUNKS + blockIdx.x] = cnt[b];
}

// ---------------- generic 3-kernel exclusive scan (multi-block) ----------------
__global__ __launch_bounds__(256)
void block_sums_kernel(const int* __restrict__ v, int* __restrict__ bsums, int n) {
    __shared__ int s[256];
    int i = blockIdx.x * 256 + threadIdx.x;
    s[threadIdx.x] = (i < n) ? v[i] : 0;
    __syncthreads();
    for (int d = 128; d > 0; d >>= 1) {
        if (threadIdx.x < d) s[threadIdx.x] += s[threadIdx.x + d];
        __syncthreads();
    }
    if (threadIdx.x == 0) bsums[blockIdx.x] = s[0];
}

__global__ __launch_bounds__(512)
void scan_bsums_kernel(const int* __restrict__ bsums, int* __restrict__ boff, int nb) {
    __shared__ int s[512];
    int v = (threadIdx.x < nb) ? bsums[threadIdx.x] : 0;
    s[threadIdx.x] = v;
    __syncthreads();
    for (int d = 1; d < 512; d <<= 1) {
        int t = (threadIdx.x >= d) ? s[threadIdx.x - d] : 0;
        __syncthreads();
        s[threadIdx.x] += t;
        __syncthreads();
    }
    if (threadIdx.x < nb) boff[threadIdx.x] = s[threadIdx.x] - v;  // exclusive
}

__global__ __launch_bounds__(256)
void scan_chunks_kernel(const int* __restrict__ v, const int* __restrict__ boff,
                        int* __restrict__ out, int n) {
    __shared__ int s[256];
    int i = blockIdx.x * 256 + threadIdx.x;
    int val = (i < n) ? v[i] : 0;
    s[threadIdx.x] = val;
    __syncthreads();
    for (int d = 1; d < 256; d <<= 1) {
        int t = (threadIdx.x >= d) ? s[threadIdx.x - d] : 0;
        __syncthreads();
        s[threadIdx.x] += t;
        __syncthreads();
    }
    if (i < n) out[i] = boff[blockIdx.x] + s[threadIdx.x] - val;  // exclusive
}

// ---------------- Pass 2: place edges into (bucket,chunk) runs ----------------
// payload: .x = src | (dst_local << 17) as bits, .y = weight
__global__ __launch_bounds__(256)
void place_kernel(const int* __restrict__ src, const int* __restrict__ dst,
                  const float* __restrict__ ew, const int* __restrict__ gofs,
                  float2* __restrict__ binned) {
    __shared__ int lcur[NBUCK];
    for (int i = threadIdx.x; i < NBUCK; i += 256) lcur[i] = 0;
    __syncthreads();
    const int base = blockIdx.x * CHUNK;
    const int end = min(base + CHUNK, NE);
    for (int e = base + threadIdx.x; e < end; e += 256) {
        int d = dst[e];
        int b = d >> BUCKET_BITS;
        int p = gofs[b * NCHUNKS + blockIdx.x] + atomicAdd(&lcur[b], 1);
        float2 pk;
        pk.x = __int_as_float(src[e] | ((d & (BNODES - 1)) << 17));
        pk.y = ew[e];
        binned[p] = pk;
    }
}

// ---------------- Pass 3: per-bucket LDS counting sort by (dst_local, src_tile) ----------------
__global__ __launch_bounds__(256)
void bucket_sort_kernel(const float2* __restrict__ binned, const int* __restrict__ gofs,
                        float2* __restrict__ edges, int* __restrict__ off) {
    __shared__ float2 buf[BUFCAP];
    __shared__ int pos[NKEY];
    __shared__ int psum[256];
    const int tid = threadIdx.x;
    const int b = blockIdx.x;
    const int s = gofs[b * NCHUNKS];
    const int e = (b == NBUCK - 1) ? NE : gofs[(b + 1) * NCHUNKS];
    const int n = e - s;

    for (int i = tid; i < NKEY; i += 256) pos[i] = 0;
    __syncthreads();
    for (int i = tid; i < n; i += 256) {
        int v = __float_as_int(binned[s + i].x);
        int dl = (v >> 17) & (BNODES - 1);
        int t = (v & 0x1FFFF) >> TILE_SHIFT;
        atomicAdd(&pos[(dl << 3) | t], 1);
    }
    __syncthreads();
    constexpr int PER = NKEY / 256;              // 8
    const int base = tid * PER;
    int run = 0;
#pragma unroll
    for (int i = 0; i < PER; ++i) { int c = pos[base + i]; pos[base + i] = run; run += c; }
    psum[tid] = run;
    __syncthreads();
    for (int d = 1; d < 256; d <<= 1) {
        int t = (tid >= d) ? psum[tid - d] : 0;
        __syncthreads();
        psum[tid] += t;
        __syncthreads();
    }
    const int chunk_off = psum[tid] - run;
#pragma unroll
    for (int i = 0; i < PER; ++i) pos[base + i] += chunk_off;
    __syncthreads();
    const int node0 = b * BNODES;
    if (tid < BNODES) {
        int node = node0 + tid;
        if (node < NN) off[node] = s + pos[tid << 3];
    }
    if (b == NBUCK - 1 && tid == 0) off[NN] = NE;
    __syncthreads();
    for (int i = tid; i < n; i += 256) {
        float2 pk = binned[s + i];
        int v = __float_as_int(pk.x);
        int dl = (v >> 17) & (BNODES - 1);
        int t = (v & 0x1FFFF) >> TILE_SHIFT;
        int p = atomicAdd(&pos[(dl << 3) | t], 1);
        pk.x = __int_as_float(v & 0x1FFFF);      // strip dst_local
        if (p < BUFCAP) buf[p] = pk;
    }
    __syncthreads();
    const int m = (n < BUFCAP) ? n : BUFCAP;
    for (int i = tid; i < m; i += 256)
        edges[s + i] = buf[i];
}

// ---------------- Aggregation (free-running, no barriers) ----------------
// One node per 32-lane half-wave; 8 nodes per 256-thread block.
// BF16OUT: pack 2 features into one uint store; else fp32 float2 (+bias).
template<int D, bool BIAS, bool BF16OUT>
__global__ __launch_bounds__(256)
void agg_kernel(const unsigned short* __restrict__ h, const float2* __restrict__ edges,
                const int* __restrict__ off, unsigned int* __restrict__ y16,
                float* __restrict__ yf, const float* __restrict__ bias) {
    constexpr int NU = D / 2;
    const unsigned int* __restrict__ h32 = (const unsigned int*)h;
    const int fl = threadIdx.x & 31;
    const int v = blockIdx.x * 8 + (threadIdx.x >> 5);
    if (v >= NN) return;
    if (fl >= NU) return;
    const int s = off[v], e = off[v + 1];
    float a0 = 0.f, a1 = 0.f, b0 = 0.f, b1 = 0.f;
    float c0 = 0.f, c1 = 0.f, d0 = 0.f, d1 = 0.f;
    int j = s;
    for (; j + 7 < e; j += 8) {
        float2 p0 = edges[j + 0], p1 = edges[j + 1], p2 = edges[j + 2], p3 = edges[j + 3];
        float2 p4 = edges[j + 4], p5 = edges[j + 5], p6 = edges[j + 6], p7 = edges[j + 7];
        unsigned int h0 = h32[(size_t)__float_as_int(p0.x) * NU + fl];
        unsigned int h1 = h32[(size_t)__float_as_int(p1.x) * NU + fl];
        unsigned int h2 = h32[(size_t)__float_as_int(p2.x) * NU + fl];
        unsigned int h3 = h32[(size_t)__float_as_int(p3.x) * NU + fl];
        unsigned int h4 = h32[(size_t)__float_as_int(p4.x) * NU + fl];
        unsigned int h5 = h32[(size_t)__float_as_int(p5.x) * NU + fl];
        unsigned int h6 = h32[(size_t)__float_as_int(p6.x) * NU + fl];
        unsigned int h7 = h32[(size_t)__float_as_int(p7.x) * NU + fl];
        a0 += bf2f((unsigned short)h0) * p0.y + bf2f((unsigned short)h1) * p1.y;
        a1 += bf2f((unsigned short)(h0 >> 16)) * p0.y + bf2f((unsigned short)(h1 >> 16)) * p1.y;
        b0 += bf2f((unsigned short)h2) * p2.y + bf2f((unsigned short)h3) * p3.y;
        b1 += bf2f((unsigned short)(h2 >> 16)) * p2.y + bf2f((unsigned short)(h3 >> 16)) * p3.y;
        c0 += bf2f((unsigned short)h4) * p4.y + bf2f((unsigned short)h5) * p5.y;
        c1 += bf2f((unsigned short)(h4 >> 16)) * p4.y + bf2f((unsigned short)(h5 >> 16)) * p5.y;
        d0 += bf2f((unsigned short)h6) * p6.y + bf2f((unsigned short)h7) * p7.y;
        d1 += bf2f((unsigned short)(h6 >> 16)) * p6.y + bf2f((unsigned short)(h7 >> 16)) * p7.y;
    }
    for (; j + 3 < e; j += 4) {
        float2 p0 = edges[j + 0], p1 = edges[j + 1], p2 = edges[j + 2], p3 = edges[j + 3];
        unsigned int h0 = h32[(size_t)__float_as_int(p0.x) * NU + fl];
        unsigned int h1 = h32[(size_t)__float_as_int(p1.x) * NU + fl];
        unsigned int h2 = h32[(size_t)__float_as_int(p2.x) * NU + fl];
        unsigned int h3 = h32[(size_t)__float_as_int(p3.x) * NU + fl];
        a0 += bf2f((unsigned short)h0) * p0.y + bf2f((unsigned short)h1) * p1.y;
        a1 += bf2f((unsigned short)(h0 >> 16)) * p0.y + bf2f((unsigned short)(h1 >> 16)) * p1.y;
        b0 += bf2f((unsigned short)h2) * p2.y + bf2f((unsigned short)h3) * p3.y;
        b1 += bf2f((unsigned short)(h2 >> 16)) * p2.y + bf2f((unsigned short)(h3 >> 16)) * p3.y;
    }
    for (; j < e; ++j) {
        float2 p0 = edges[j];
        unsigned int h0 = h32[(size_t)__float_as_int(p0.x) * NU + fl];
        c0 += bf2f((unsigned short)h0) * p0.y;
        c1 += bf2f((unsigned short)(h0 >> 16)) * p0.y;
    }
    float r0 = (a0 + b0) + (c0 + d0);
    float r1 = (a1 + b1) + (c1 + d1);
    if (BIAS) { r0 += bias[2 * fl]; r1 += bias[2 * fl + 1]; }
    if (BF16OUT) {
        unsigned int pk = (unsigned int)f2bf(r0) | ((unsigned int)f2bf(r1) << 16);
        y16[(size_t)v * NU + fl] = pk;
    } else {
        *(float2*)&yf[(size_t)v * D + 2 * fl] = make_float2(r0, r1);
    }
}

// ---------------- BN stats over bf16 rows: stats[0..63]=sum, stats[64..127]=sumsq ----------------
__global__ __launch_bounds__(256)
void bn_stats_bf16_kernel(const unsigned int* __restrict__ x32, float* __restrict__ stats, int n) {
    __shared__ float s0[256], s1[256], q0[256], q1[256];
    const int tid = threadIdx.x;
    const int fl = tid & 31;
    const int rg = tid >> 5;
    float sum0 = 0.f, sum1 = 0.f, sq0 = 0.f, sq1 = 0.f;
    for (int r = blockIdx.x * 8 + rg; r < n; r += gridDim.x * 8) {
        unsigned int u = x32[(size_t)r * 32 + fl];
        float v0 = bf2f((unsigned short)u);
        float v1 = bf2f((unsigned short)(u >> 16));
        sum0 += v0; sum1 += v1;
        sq0 += v0 * v0; sq1 += v1 * v1;
    }
    s0[tid] = sum0; s1[tid] = sum1; q0[tid] = sq0; q1[tid] = sq1;
    __syncthreads();
    if (tid < 32) {
        float ts0 = 0.f, ts1 = 0.f, tq0 = 0.f, tq1 = 0.f;
#pragma unroll
        for (int k = 0; k < 8; ++k) {
            ts0 += s0[tid + 32 * k]; ts1 += s1[tid + 32 * k];
            tq0 += q0[tid + 32 * k]; tq1 += q1[tid + 32 * k];
        }
        atomicAdd(&stats[2 * tid], ts0);
        atomicAdd(&stats[2 * tid + 1], ts1);
        atomicAdd(&stats[64 + 2 * tid], tq0);
        atomicAdd(&stats[64 + 2 * tid + 1], tq1);
    }
}

extern "C" void kernel_launch(void* const* d_in, const int* in_sizes, int n_in,
                              void* d_out, int out_size, void* d_ws, size_t ws_size,
                              hipStream_t stream) {
    const float* nf    = (const float*)d_in[0];
    const int*   ei    = (const int*)d_in[1];   // [2][E]
    const float* ew    = (const float*)d_in[2];
    const float* W1    = (const float*)d_in[3];
    // b1 (d_in[4]) cancels inside BN
    const float* g1    = (const float*)d_in[5];
    const float* beta1 = (const float*)d_in[6];
    const float* W2    = (const float*)d_in[7];
    // b2 (d_in[8]) cancels inside BN
    const float* g2    = (const float*)d_in[9];
    const float* beta2 = (const float*)d_in[10];
    const float* W3    = (const float*)d_in[11];
    const float* b3    = (const float*)d_in[12];

    const int* src = ei;
    const int* dst = ei + NE;

    // workspace layout (4B units)
    unsigned short* hbuf = (unsigned short*)d_ws;        // NN*64 bf16 (12.8MB); binned aliases it
    unsigned short* abuf = hbuf + (size_t)NN * 64;       // NN*64 bf16 (agg output)
    float2* edges  = (float2*)(abuf + (size_t)NN * 64);  // NE float2
    int*    off    = (int*)(edges + NE);                 // NN+1
    int*    counts = off + NN + 1;                       // SCAN_N
    int*    gofs   = counts + SCAN_N;                    // SCAN_N
    int*    bsums  = gofs + SCAN_N;                      // 512
    int*    boff   = bsums + 512;                        // 512
    float*  stats1 = (float*)(boff + 512);               // 128
    float*  stats2 = stats1 + 128;                       // 128

    float2* binned = (float2*)hbuf;                      // scratch, consumed before gemm1

    float* out = (float*)d_out;

    const int SB = (SCAN_N + 255) / 256;   // 391
    const int ggrid = (NN + 63) / 64;      // 1563
    const int agrid = (NN + 7) / 8;        // 12500

    // ---------- zero stats banks ----------
    (void)hipMemsetAsync(stats1, 0, 256 * sizeof(float), stream);

    // ---------- CSR build: hist -> 3-kernel scan -> place -> bucket sort ----------
    hist_kernel<<<NCHUNKS, 256, 0, stream>>>(dst, counts);
    block_sums_kernel<<<SB, 256, 0, stream>>>(counts, bsums, SCAN_N);
    scan_bsums_kernel<<<1, 512, 0, stream>>>(bsums, boff, SB);
    scan_chunks_kernel<<<SB, 256, 0, stream>>>(counts, boff, gofs, SCAN_N);
    place_kernel<<<NCHUNKS, 256, 0, stream>>>(src, dst, ew, gofs, binned);
    bucket_sort_kernel<<<NBUCK, 256, 0, stream>>>(binned, gofs, edges, off);

    // ---------- layer 1: GCNConv(128->64); agg -> bf16; stats1 ----------
    gemm_mfma_kernel<128, 64, 4, false, false><<<ggrid, 256, 0, stream>>>(
        nf, W1, hbuf, NN, nullptr, nullptr, nullptr);
    agg_kernel<64, false, true><<<agrid, 256, 0, stream>>>(
        hbuf, edges, off, (unsigned int*)abuf, nullptr, nullptr);
    bn_stats_bf16_kernel<<<512, 256, 0, stream>>>((const unsigned int*)abuf, stats1, NN);

    // ---------- layer 2: BN1+ReLU fused in GEMM; agg -> bf16; stats2 ----------
    gemm_mfma_kernel<64, 64, 4, true, true><<<ggrid, 256, 0, stream>>>(
        abuf, W2, hbuf, NN, stats1, g1, beta1);
    agg_kernel<64, false, true><<<agrid, 256, 0, stream>>>(
        hbuf, edges, off, (unsigned int*)abuf, nullptr, nullptr);
    bn_stats_bf16_kernel<<<512, 256, 0, stream>>>((const unsigned int*)abuf, stats2, NN);

    // ---------- layer 3: BN2+ReLU fused in GEMM; agg + b3 -> out (fp32) ----------
    gemm_mfma_kernel<64, 40, 3, true, true><<<ggrid, 256, 0, stream>>>(
        abuf, W3, hbuf, NN, stats2, g2, beta2);
    agg_kernel<40, true, false><<<agrid, 256, 0, stream>>>(
        hbuf, edges, off, nullptr, out, b3);
}

// Round 15
// 252.563 us; speedup vs baseline: 1.6248x; 1.0418x over previous
//
#include <hip/hip_runtime.h>
#include <math.h>

#define NN 100000
#define NE 1200000
#define EPSV 1e-5f

// binning geometry
#define BUCKET_BITS 8
#define BNODES 256                               // nodes per bucket
#define NBUCK ((NN + BNODES - 1) / BNODES)       // 391
#define NCHUNKS 256
#define CHUNK ((NE + NCHUNKS - 1) / NCHUNKS)     // 4688
#define SCAN_N (NBUCK * NCHUNKS)                 // 100096
#define BUFCAP 4096                              // max edges per bucket (mean 3072)
#define TILE_SHIFT 14                            // src tile = src >> 14
#define NKEY 2048                                // 256 dst_local x 8 tiles

typedef __attribute__((ext_vector_type(8))) short short8;
typedef __attribute__((ext_vector_type(4))) float f32x4;

__device__ __forceinline__ unsigned short f2bf(float f) {
    unsigned int u = __float_as_uint(f);
    u += 0x7FFF + ((u >> 16) & 1);               // round-to-nearest-even
    return (unsigned short)(u >> 16);
}
__device__ __forceinline__ float bf2f(unsigned short u) {
    return __uint_as_float(((unsigned int)u) << 16);
}

// ---------------- MFMA GEMM: Y[n x DOUT](bf16) = X[n x DIN] @ W[DIN x DOUT](fp32) ----------------
// 256 threads = 4 waves; 64 rows/block; wave w owns rows w*16..+15, all DOUT cols.
// BNRELU: scale/shift recomputed per block from stats[128]+g+beta.
// BF16IN: X rows are bf16 (agg output); else fp32.
template<int DIN, int DOUT, int NF, bool BNRELU, bool BF16IN>
__global__ __launch_bounds__(256)
void gemm_mfma_kernel(const void* __restrict__ Xv, const float* __restrict__ W,
                      unsigned short* __restrict__ Y, int n,
                      const float* __restrict__ stats, const float* __restrict__ g,
                      const float* __restrict__ beta) {
    constexpr int LD = DIN + 8;                  // bf16 units
    constexpr int DP = NF * 16;                  // padded col count
    static_assert(DIN % 32 == 0, "K multiple of 32");
    __shared__ unsigned short Xs[64][LD];
    __shared__ unsigned short Wt[DP][LD];
    __shared__ float sc_s[64], sh_s[64];

    const int tid = threadIdx.x;
    const int row0 = blockIdx.x * 64;

    if (BNRELU) {
        if (tid < 64) {
            float mu = stats[tid] * (1.f / NN);
            float var = stats[64 + tid] * (1.f / NN) - mu * mu;
            float rs = rsqrtf(var + EPSV);
            float sc = g[tid] * rs;
            sc_s[tid] = sc;
            sh_s[tid] = beta[tid] - mu * sc;
        }
        __syncthreads();
    }

    // ---- stage X tile -> bf16 (optionally BN+ReLU) ----
    for (int i = tid; i < 64 * (DIN / 4); i += 256) {
        int r = i / (DIN / 4);
        int c4 = i % (DIN / 4);
        int gr = row0 + r;
        float v0 = 0.f, v1 = 0.f, v2 = 0.f, v3 = 0.f;
        if (gr < n) {
            if (BF16IN) {
                const unsigned short* Xb = (const unsigned short*)Xv;
                ushort4 u = *(const ushort4*)&Xb[(size_t)gr * DIN + c4 * 4];
                v0 = bf2f(u.x); v1 = bf2f(u.y); v2 = bf2f(u.z); v3 = bf2f(u.w);
            } else {
                const float* Xf = (const float*)Xv;
                float4 f = *(const float4*)&Xf[(size_t)gr * DIN + c4 * 4];
                v0 = f.x; v1 = f.y; v2 = f.z; v3 = f.w;
            }
        }
        if (BNRELU) {
            int c = c4 * 4;
            v0 = fmaxf(v0 * sc_s[c + 0] + sh_s[c + 0], 0.f);
            v1 = fmaxf(v1 * sc_s[c + 1] + sh_s[c + 1], 0.f);
            v2 = fmaxf(v2 * sc_s[c + 2] + sh_s[c + 2], 0.f);
            v3 = fmaxf(v3 * sc_s[c + 3] + sh_s[c + 3], 0.f);
        }
        ushort4 o;
        o.x = f2bf(v0); o.y = f2bf(v1); o.z = f2bf(v2); o.w = f2bf(v3);
        *(ushort4*)&Xs[r][c4 * 4] = o;
    }
    // ---- stage W transposed (fp32 -> bf16), zero-pad cols >= DOUT ----
    for (int i = tid; i < DIN * DOUT; i += 256) {
        int k = i / DOUT;
        int c = i - k * DOUT;
        Wt[c][k] = f2bf(W[i]);
    }
    if (DP > DOUT) {
        for (int i = tid; i < DIN * (DP - DOUT); i += 256) {
            int k = i / (DP - DOUT);
            int c = DOUT + (i - k * (DP - DOUT));
            Wt[c][k] = 0;
        }
    }
    __syncthreads();

    const int w = tid >> 6;
    const int lane = tid & 63;
    const int lr = lane & 15;
    const int kg = lane >> 4;

    f32x4 acc[NF];
#pragma unroll
    for (int nf = 0; nf < NF; ++nf) acc[nf] = (f32x4){0.f, 0.f, 0.f, 0.f};

#pragma unroll
    for (int t = 0; t < DIN / 32; ++t) {
        const int kb = t * 32 + kg * 8;
        short8 a = *(const short8*)&Xs[w * 16 + lr][kb];
#pragma unroll
        for (int nf = 0; nf < NF; ++nf) {
            short8 b = *(const short8*)&Wt[nf * 16 + lr][kb];
            acc[nf] = __builtin_amdgcn_mfma_f32_16x16x32_bf16(a, b, acc[nf], 0, 0, 0);
        }
    }

    // ---- C write: row=(kg*4+j), col=nf*16+lr ----
#pragma unroll
    for (int nf = 0; nf < NF; ++nf) {
        const int c = nf * 16 + lr;
        if (c < DOUT) {
#pragma unroll
            for (int j = 0; j < 4; ++j) {
                int gr = row0 + w * 16 + kg * 4 + j;
                if (gr < n)
                    Y[(size_t)gr * DOUT + c] = f2bf(acc[nf][j]);
            }
        }
    }
}

// ---------------- Pass 1: per-chunk bucket histogram ----------------
__global__ __launch_bounds__(256)
void hist_kernel(const int* __restrict__ dst, int* __restrict__ counts) {
    __shared__ int cnt[NBUCK];
    for (int i = threadIdx.x; i < NBUCK; i += 256) cnt[i] = 0;
    __syncthreads();
    const int base = blockIdx.x * CHUNK;
    const int end = min(base + CHUNK, NE);
    for (int e = base + threadIdx.x; e < end; e += 256)
        atomicAdd(&cnt[dst[e] >> BUCKET_BITS], 1);
    __syncthreads();
    for (int b = threadIdx.x; b < NBUCK; b += 256)
        counts[b * NCHUNKS + blockIdx.x] = cnt[b];
}

// ---------------- generic 3-kernel exclusive scan (multi-block) ----------------
__global__ __launch_bounds__(256)
void block_sums_kernel(const int* __restrict__ v, int* __restrict__ bsums, int n) {
    __shared__ int s[256];
    int i = blockIdx.x * 256 + threadIdx.x;
    s[threadIdx.x] = (i < n) ? v[i] : 0;
    __syncthreads();
    for (int d = 128; d > 0; d >>= 1) {
        if (threadIdx.x < d) s[threadIdx.x] += s[threadIdx.x + d];
        __syncthreads();
    }
    if (threadIdx.x == 0) bsums[blockIdx.x] = s[0];
}

__global__ __launch_bounds__(512)
void scan_bsums_kernel(const int* __restrict__ bsums, int* __restrict__ boff, int nb) {
    __shared__ int s[512];
    int v = (threadIdx.x < nb) ? bsums[threadIdx.x] : 0;
    s[threadIdx.x] = v;
    __syncthreads();
    for (int d = 1; d < 512; d <<= 1) {
        int t = (threadIdx.x >= d) ? s[threadIdx.x - d] : 0;
        __syncthreads();
        s[threadIdx.x] += t;
        __syncthreads();
    }
    if (threadIdx.x < nb) boff[threadIdx.x] = s[threadIdx.x] - v;  // exclusive
}

__global__ __launch_bounds__(256)
void scan_chunks_kernel(const int* __restrict__ v, const int* __restrict__ boff,
                        int* __restrict__ out, int n) {
    __shared__ int s[256];
    int i = blockIdx.x * 256 + threadIdx.x;
    int val = (i < n) ? v[i] : 0;
    s[threadIdx.x] = val;
    __syncthreads();
    for (int d = 1; d < 256; d <<= 1) {
        int t = (threadIdx.x >= d) ? s[threadIdx.x - d] : 0;
        __syncthreads();
        s[threadIdx.x] += t;
        __syncthreads();
    }
    if (i < n) out[i] = boff[blockIdx.x] + s[threadIdx.x] - val;  // exclusive
}

// ---------------- Pass 2: place edges into (bucket,chunk) runs ----------------
// payload: .x = src | (dst_local << 17) as bits, .y = weight
__global__ __launch_bounds__(256)
void place_kernel(const int* __restrict__ src, const int* __restrict__ dst,
                  const float* __restrict__ ew, const int* __restrict__ gofs,
                  float2* __restrict__ binned) {
    __shared__ int lcur[NBUCK];
    for (int i = threadIdx.x; i < NBUCK; i += 256) lcur[i] = 0;
    __syncthreads();
    const int base = blockIdx.x * CHUNK;
    const int end = min(base + CHUNK, NE);
    for (int e = base + threadIdx.x; e < end; e += 256) {
        int d = dst[e];
        int b = d >> BUCKET_BITS;
        int p = gofs[b * NCHUNKS + blockIdx.x] + atomicAdd(&lcur[b], 1);
        float2 pk;
        pk.x = __int_as_float(src[e] | ((d & (BNODES - 1)) << 17));
        pk.y = ew[e];
        binned[p] = pk;
    }
}

// ---------------- Pass 3: per-bucket LDS counting sort by (dst_local, src_tile) ----------------
__global__ __launch_bounds__(256)
void bucket_sort_kernel(const float2* __restrict__ binned, const int* __restrict__ gofs,
                        float2* __restrict__ edges, int* __restrict__ off) {
    __shared__ float2 buf[BUFCAP];
    __shared__ int pos[NKEY];
    __shared__ int psum[256];
    const int tid = threadIdx.x;
    const int b = blockIdx.x;
    const int s = gofs[b * NCHUNKS];
    const int e = (b == NBUCK - 1) ? NE : gofs[(b + 1) * NCHUNKS];
    const int n = e - s;

    for (int i = tid; i < NKEY; i += 256) pos[i] = 0;
    __syncthreads();
    for (int i = tid; i < n; i += 256) {
        int v = __float_as_int(binned[s + i].x);
        int dl = (v >> 17) & (BNODES - 1);
        int t = (v & 0x1FFFF) >> TILE_SHIFT;
        atomicAdd(&pos[(dl << 3) | t], 1);
    }
    __syncthreads();
    constexpr int PER = NKEY / 256;              // 8
    const int base = tid * PER;
    int run = 0;
#pragma unroll
    for (int i = 0; i < PER; ++i) { int c = pos[base + i]; pos[base + i] = run; run += c; }
    psum[tid] = run;
    __syncthreads();
    for (int d = 1; d < 256; d <<= 1) {
        int t = (tid >= d) ? psum[tid - d] : 0;
        __syncthreads();
        psum[tid] += t;
        __syncthreads();
    }
    const int chunk_off = psum[tid] - run;
#pragma unroll
    for (int i = 0; i < PER; ++i) pos[base + i] += chunk_off;
    __syncthreads();
    const int node0 = b * BNODES;
    if (tid < BNODES) {
        int node = node0 + tid;
        if (node < NN) off[node] = s + pos[tid << 3];
    }
    if (b == NBUCK - 1 && tid == 0) off[NN] = NE;
    __syncthreads();
    for (int i = tid; i < n; i += 256) {
        float2 pk = binned[s + i];
        int v = __float_as_int(pk.x);
        int dl = (v >> 17) & (BNODES - 1);
        int t = (v & 0x1FFFF) >> TILE_SHIFT;
        int p = atomicAdd(&pos[(dl << 3) | t], 1);
        pk.x = __int_as_float(v & 0x1FFFF);      // strip dst_local
        if (p < BUFCAP) buf[p] = pk;
    }
    __syncthreads();
    const int m = (n < BUFCAP) ? n : BUFCAP;
    for (int i = tid; i < m; i += 256)
        edges[s + i] = buf[i];
}

// ---------------- Aggregation (quarter-wave, free-running) ----------------
// One node per 16-lane quarter-wave; lane loads uint2 = 4 bf16 features (16x8B = full
// 128B row for D=64). 16 nodes per 256-thread block -> 4 independent gather streams
// per wave (2x the half-wave version's MLP).
template<int D, bool BIAS, bool BF16OUT>
__global__ __launch_bounds__(256)
void agg_kernel(const unsigned short* __restrict__ h, const float2* __restrict__ edges,
                const int* __restrict__ off, uint2* __restrict__ y16,
                float* __restrict__ yf, const float* __restrict__ bias) {
    constexpr int NU = D / 4;                    // uint2 per row
    const uint2* __restrict__ h64 = (const uint2*)h;
    const int fl = threadIdx.x & 15;
    const int v = blockIdx.x * 16 + (threadIdx.x >> 4);
    if (v >= NN) return;
    if (fl >= NU) return;
    const int s = off[v], e = off[v + 1];
    float A0 = 0.f, A1 = 0.f, A2 = 0.f, A3 = 0.f;
    float B0 = 0.f, B1 = 0.f, B2 = 0.f, B3 = 0.f;
    int j = s;
    for (; j + 7 < e; j += 8) {
        float2 p0 = edges[j + 0], p1 = edges[j + 1], p2 = edges[j + 2], p3 = edges[j + 3];
        float2 p4 = edges[j + 4], p5 = edges[j + 5], p6 = edges[j + 6], p7 = edges[j + 7];
        uint2 g0 = h64[(size_t)__float_as_int(p0.x) * NU + fl];
        uint2 g1 = h64[(size_t)__float_as_int(p1.x) * NU + fl];
        uint2 g2 = h64[(size_t)__float_as_int(p2.x) * NU + fl];
        uint2 g3 = h64[(size_t)__float_as_int(p3.x) * NU + fl];
        uint2 g4 = h64[(size_t)__float_as_int(p4.x) * NU + fl];
        uint2 g5 = h64[(size_t)__float_as_int(p5.x) * NU + fl];
        uint2 g6 = h64[(size_t)__float_as_int(p6.x) * NU + fl];
        uint2 g7 = h64[(size_t)__float_as_int(p7.x) * NU + fl];
        A0 += bf2f((unsigned short)g0.x) * p0.y + bf2f((unsigned short)g1.x) * p1.y;
        A1 += bf2f((unsigned short)(g0.x >> 16)) * p0.y + bf2f((unsigned short)(g1.x >> 16)) * p1.y;
        A2 += bf2f((unsigned short)g0.y) * p0.y + bf2f((unsigned short)g1.y) * p1.y;
        A3 += bf2f((unsigned short)(g0.y >> 16)) * p0.y + bf2f((unsigned short)(g1.y >> 16)) * p1.y;
        B0 += bf2f((unsigned short)g2.x) * p2.y + bf2f((unsigned short)g3.x) * p3.y;
        B1 += bf2f((unsigned short)(g2.x >> 16)) * p2.y + bf2f((unsigned short)(g3.x >> 16)) * p3.y;
        B2 += bf2f((unsigned short)g2.y) * p2.y + bf2f((unsigned short)g3.y) * p3.y;
        B3 += bf2f((unsigned short)(g2.y >> 16)) * p2.y + bf2f((unsigned short)(g3.y >> 16)) * p3.y;
        A0 += bf2f((unsigned short)g4.x) * p4.y + bf2f((unsigned short)g5.x) * p5.y;
        A1 += bf2f((unsigned short)(g4.x >> 16)) * p4.y + bf2f((unsigned short)(g5.x >> 16)) * p5.y;
        A2 += bf2f((unsigned short)g4.y) * p4.y + bf2f((unsigned short)g5.y) * p5.y;
        A3 += bf2f((unsigned short)(g4.y >> 16)) * p4.y + bf2f((unsigned short)(g5.y >> 16)) * p5.y;
        B0 += bf2f((unsigned short)g6.x) * p6.y + bf2f((unsigned short)g7.x) * p7.y;
        B1 += bf2f((unsigned short)(g6.x >> 16)) * p6.y + bf2f((unsigned short)(g7.x >> 16)) * p7.y;
        B2 += bf2f((unsigned short)g6.y) * p6.y + bf2f((unsigned short)g7.y) * p7.y;
        B3 += bf2f((unsigned short)(g6.y >> 16)) * p6.y + bf2f((unsigned short)(g7.y >> 16)) * p7.y;
    }
    for (; j + 1 < e; j += 2) {
        float2 p0 = edges[j], p1 = edges[j + 1];
        uint2 g0 = h64[(size_t)__float_as_int(p0.x) * NU + fl];
        uint2 g1 = h64[(size_t)__float_as_int(p1.x) * NU + fl];
        A0 += bf2f((unsigned short)g0.x) * p0.y + bf2f((unsigned short)g1.x) * p1.y;
        A1 += bf2f((unsigned short)(g0.x >> 16)) * p0.y + bf2f((unsigned short)(g1.x >> 16)) * p1.y;
        A2 += bf2f((unsigned short)g0.y) * p0.y + bf2f((unsigned short)g1.y) * p1.y;
        A3 += bf2f((unsigned short)(g0.y >> 16)) * p0.y + bf2f((unsigned short)(g1.y >> 16)) * p1.y;
    }
    if (j < e) {
        float2 p0 = edges[j];
        uint2 g0 = h64[(size_t)__float_as_int(p0.x) * NU + fl];
        B0 += bf2f((unsigned short)g0.x) * p0.y;
        B1 += bf2f((unsigned short)(g0.x >> 16)) * p0.y;
        B2 += bf2f((unsigned short)g0.y) * p0.y;
        B3 += bf2f((unsigned short)(g0.y >> 16)) * p0.y;
    }
    float r0 = A0 + B0, r1 = A1 + B1, r2 = A2 + B2, r3 = A3 + B3;
    if (BIAS) {
        r0 += bias[4 * fl];     r1 += bias[4 * fl + 1];
        r2 += bias[4 * fl + 2]; r3 += bias[4 * fl + 3];
    }
    if (BF16OUT) {
        uint2 pk;
        pk.x = (unsigned int)f2bf(r0) | ((unsigned int)f2bf(r1) << 16);
        pk.y = (unsigned int)f2bf(r2) | ((unsigned int)f2bf(r3) << 16);
        y16[(size_t)v * NU + fl] = pk;
    } else {
        float4 o = make_float4(r0, r1, r2, r3);
        *(float4*)&yf[(size_t)v * D + 4 * fl] = o;
    }
}

// ---------------- BN stats over bf16 rows: stats[0..63]=sum, stats[64..127]=sumsq ----------------
__global__ __launch_bounds__(256)
void bn_stats_bf16_kernel(const unsigned int* __restrict__ x32, float* __restrict__ stats, int n) {
    __shared__ float s0[256], s1[256], q0[256], q1[256];
    const int tid = threadIdx.x;
    const int fl = tid & 31;
    const int rg = tid >> 5;
    float sum0 = 0.f, sum1 = 0.f, sq0 = 0.f, sq1 = 0.f;
    for (int r = blockIdx.x * 8 + rg; r < n; r += gridDim.x * 8) {
        unsigned int u = x32[(size_t)r * 32 + fl];
        float v0 = bf2f((unsigned short)u);
        float v1 = bf2f((unsigned short)(u >> 16));
        sum0 += v0; sum1 += v1;
        sq0 += v0 * v0; sq1 += v1 * v1;
    }
    s0[tid] = sum0; s1[tid] = sum1; q0[tid] = sq0; q1[tid] = sq1;
    __syncthreads();
    if (tid < 32) {
        float ts0 = 0.f, ts1 = 0.f, tq0 = 0.f, tq1 = 0.f;
#pragma unroll
        for (int k = 0; k < 8; ++k) {
            ts0 += s0[tid + 32 * k]; ts1 += s1[tid + 32 * k];
            tq0 += q0[tid + 32 * k]; tq1 += q1[tid + 32 * k];
        }
        atomicAdd(&stats[2 * tid], ts0);
        atomicAdd(&stats[2 * tid + 1], ts1);
        atomicAdd(&stats[64 + 2 * tid], tq0);
        atomicAdd(&stats[64 + 2 * tid + 1], tq1);
    }
}

extern "C" void kernel_launch(void* const* d_in, const int* in_sizes, int n_in,
                              void* d_out, int out_size, void* d_ws, size_t ws_size,
                              hipStream_t stream) {
    const float* nf    = (const float*)d_in[0];
    const int*   ei    = (const int*)d_in[1];   // [2][E]
    const float* ew    = (const float*)d_in[2];
    const float* W1    = (const float*)d_in[3];
    // b1 (d_in[4]) cancels inside BN
    const float* g1    = (const float*)d_in[5];
    const float* beta1 = (const float*)d_in[6];
    const float* W2    = (const float*)d_in[7];
    // b2 (d_in[8]) cancels inside BN
    const float* g2    = (const float*)d_in[9];
    const float* beta2 = (const float*)d_in[10];
    const float* W3    = (const float*)d_in[11];
    const float* b3    = (const float*)d_in[12];

    const int* src = ei;
    const int* dst = ei + NE;

    // workspace layout (4B units)
    unsigned short* hbuf = (unsigned short*)d_ws;        // NN*64 bf16 (12.8MB); binned aliases it
    unsigned short* abuf = hbuf + (size_t)NN * 64;       // NN*64 bf16 (agg output)
    float2* edges  = (float2*)(abuf + (size_t)NN * 64);  // NE float2
    int*    off    = (int*)(edges + NE);                 // NN+1
    int*    counts = off + NN + 1;                       // SCAN_N
    int*    gofs   = counts + SCAN_N;                    // SCAN_N
    int*    bsums  = gofs + SCAN_N;                      // 512
    int*    boff   = bsums + 512;                        // 512
    float*  stats1 = (float*)(boff + 512);               // 128
    float*  stats2 = stats1 + 128;                       // 128

    float2* binned = (float2*)hbuf;                      // scratch, consumed before gemm1

    float* out = (float*)d_out;

    const int SB = (SCAN_N + 255) / 256;   // 391
    const int ggrid = (NN + 63) / 64;      // 1563
    const int agrid = (NN + 15) / 16;      // 6250

    // ---------- zero stats banks ----------
    (void)hipMemsetAsync(stats1, 0, 256 * sizeof(float), stream);

    // ---------- CSR build: hist -> 3-kernel scan -> place -> bucket sort ----------
    hist_kernel<<<NCHUNKS, 256, 0, stream>>>(dst, counts);
    block_sums_kernel<<<SB, 256, 0, stream>>>(counts, bsums, SCAN_N);
    scan_bsums_kernel<<<1, 512, 0, stream>>>(bsums, boff, SB);
    scan_chunks_kernel<<<SB, 256, 0, stream>>>(counts, boff, gofs, SCAN_N);
    place_kernel<<<NCHUNKS, 256, 0, stream>>>(src, dst, ew, gofs, binned);
    bucket_sort_kernel<<<NBUCK, 256, 0, stream>>>(binned, gofs, edges, off);

    // ---------- layer 1: GCNConv(128->64); agg -> bf16; stats1 ----------
    gemm_mfma_kernel<128, 64, 4, false, false><<<ggrid, 256, 0, stream>>>(
        nf, W1, hbuf, NN, nullptr, nullptr, nullptr);
    agg_kernel<64, false, true><<<agrid, 256, 0, stream>>>(
        hbuf, edges, off, (uint2*)abuf, nullptr, nullptr);
    bn_stats_bf16_kernel<<<512, 256, 0, stream>>>((const unsigned int*)abuf, stats1, NN);

    // ---------- layer 2: BN1+ReLU fused in GEMM; agg -> bf16; stats2 ----------
    gemm_mfma_kernel<64, 64, 4, true, true><<<ggrid, 256, 0, stream>>>(
        abuf, W2, hbuf, NN, stats1, g1, beta1);
    agg_kernel<64, false, true><<<agrid, 256, 0, stream>>>(
        hbuf, edges, off, (uint2*)abuf, nullptr, nullptr);
    bn_stats_bf16_kernel<<<512, 256, 0, stream>>>((const unsigned int*)abuf, stats2, NN);

    // ---------- layer 3: BN2+ReLU fused in GEMM; agg + b3 -> out (fp32) ----------
    gemm_mfma_kernel<64, 40, 3, true, true><<<ggrid, 256, 0, stream>>>(
        abuf, W3, hbuf, NN, stats2, g2, beta2);
    agg_kernel<40, true, false><<<agrid, 256, 0, stream>>>(
        hbuf, edges, off, nullptr, out, b3);
}

// Round 16
// 243.053 us; speedup vs baseline: 1.6884x; 1.0391x over previous
//
#include <hip/hip_runtime.h>
#include <math.h>

#define NN 100000
#define NE 1200000
#define EPSV 1e-5f

// binning geometry
#define BUCKET_BITS 8
#define BNODES 256                               // nodes per bucket
#define NBUCK ((NN + BNODES - 1) / BNODES)       // 391
#define NCHUNKS 256
#define CHUNK ((NE + NCHUNKS - 1) / NCHUNKS)     // 4688
#define SCAN_N (NBUCK * NCHUNKS)                 // 100096
#define BUFCAP 4096                              // max edges per bucket (mean 3072)
#define TILE_SHIFT 14                            // src tile = src >> 14
#define NKEY 2048                                // 256 dst_local x 8 tiles

typedef __attribute__((ext_vector_type(8))) short short8;
typedef __attribute__((ext_vector_type(4))) float f32x4;

__device__ __forceinline__ unsigned short f2bf(float f) {
    unsigned int u = __float_as_uint(f);
    u += 0x7FFF + ((u >> 16) & 1);               // round-to-nearest-even
    return (unsigned short)(u >> 16);
}
__device__ __forceinline__ float bf2f(unsigned short u) {
    return __uint_as_float(((unsigned int)u) << 16);
}

// ---------------- MFMA GEMM: Y[n x DOUT](bf16) = X[n x DIN] @ W[DIN x DOUT](fp32) ----------------
// 256 threads = 4 waves; 64 rows/block; wave w owns rows w*16..+15, all DOUT cols.
// BNRELU: scale/shift recomputed per block from stats[128]+g+beta.
// BF16IN: X rows are bf16 (agg output); else fp32.
template<int DIN, int DOUT, int NF, bool BNRELU, bool BF16IN>
__global__ __launch_bounds__(256)
void gemm_mfma_kernel(const void* __restrict__ Xv, const float* __restrict__ W,
                      unsigned short* __restrict__ Y, int n,
                      const float* __restrict__ stats, const float* __restrict__ g,
                      const float* __restrict__ beta) {
    constexpr int LD = DIN + 8;                  // bf16 units
    constexpr int DP = NF * 16;                  // padded col count
    static_assert(DIN % 32 == 0, "K multiple of 32");
    __shared__ unsigned short Xs[64][LD];
    __shared__ unsigned short Wt[DP][LD];
    __shared__ float sc_s[64], sh_s[64];

    const int tid = threadIdx.x;
    const int row0 = blockIdx.x * 64;

    if (BNRELU) {
        if (tid < 64) {
            float mu = stats[tid] * (1.f / NN);
            float var = stats[64 + tid] * (1.f / NN) - mu * mu;
            float rs = rsqrtf(var + EPSV);
            float sc = g[tid] * rs;
            sc_s[tid] = sc;
            sh_s[tid] = beta[tid] - mu * sc;
        }
        __syncthreads();
    }

    // ---- stage X tile -> bf16 (optionally BN+ReLU) ----
    for (int i = tid; i < 64 * (DIN / 4); i += 256) {
        int r = i / (DIN / 4);
        int c4 = i % (DIN / 4);
        int gr = row0 + r;
        float v0 = 0.f, v1 = 0.f, v2 = 0.f, v3 = 0.f;
        if (gr < n) {
            if (BF16IN) {
                const unsigned short* Xb = (const unsigned short*)Xv;
                ushort4 u = *(const ushort4*)&Xb[(size_t)gr * DIN + c4 * 4];
                v0 = bf2f(u.x); v1 = bf2f(u.y); v2 = bf2f(u.z); v3 = bf2f(u.w);
            } else {
                const float* Xf = (const float*)Xv;
                float4 f = *(const float4*)&Xf[(size_t)gr * DIN + c4 * 4];
                v0 = f.x; v1 = f.y; v2 = f.z; v3 = f.w;
            }
        }
        if (BNRELU) {
            int c = c4 * 4;
            v0 = fmaxf(v0 * sc_s[c + 0] + sh_s[c + 0], 0.f);
            v1 = fmaxf(v1 * sc_s[c + 1] + sh_s[c + 1], 0.f);
            v2 = fmaxf(v2 * sc_s[c + 2] + sh_s[c + 2], 0.f);
            v3 = fmaxf(v3 * sc_s[c + 3] + sh_s[c + 3], 0.f);
        }
        ushort4 o;
        o.x = f2bf(v0); o.y = f2bf(v1); o.z = f2bf(v2); o.w = f2bf(v3);
        *(ushort4*)&Xs[r][c4 * 4] = o;
    }
    // ---- stage W transposed (fp32 -> bf16), zero-pad cols >= DOUT ----
    for (int i = tid; i < DIN * DOUT; i += 256) {
        int k = i / DOUT;
        int c = i - k * DOUT;
        Wt[c][k] = f2bf(W[i]);
    }
    if (DP > DOUT) {
        for (int i = tid; i < DIN * (DP - DOUT); i += 256) {
            int k = i / (DP - DOUT);
            int c = DOUT + (i - k * (DP - DOUT));
            Wt[c][k] = 0;
        }
    }
    __syncthreads();

    const int w = tid >> 6;
    const int lane = tid & 63;
    const int lr = lane & 15;
    const int kg = lane >> 4;

    f32x4 acc[NF];
#pragma unroll
    for (int nf = 0; nf < NF; ++nf) acc[nf] = (f32x4){0.f, 0.f, 0.f, 0.f};

#pragma unroll
    for (int t = 0; t < DIN / 32; ++t) {
        const int kb = t * 32 + kg * 8;
        short8 a = *(const short8*)&Xs[w * 16 + lr][kb];
#pragma unroll
        for (int nf = 0; nf < NF; ++nf) {
            short8 b = *(const short8*)&Wt[nf * 16 + lr][kb];
            acc[nf] = __builtin_amdgcn_mfma_f32_16x16x32_bf16(a, b, acc[nf], 0, 0, 0);
        }
    }

    // ---- C write: row=(kg*4+j), col=nf*16+lr ----
#pragma unroll
    for (int nf = 0; nf < NF; ++nf) {
        const int c = nf * 16 + lr;
        if (c < DOUT) {
#pragma unroll
            for (int j = 0; j < 4; ++j) {
                int gr = row0 + w * 16 + kg * 4 + j;
                if (gr < n)
                    Y[(size_t)gr * DOUT + c] = f2bf(acc[nf][j]);
            }
        }
    }
}

// ---------------- Pass 1: per-chunk bucket histogram ----------------
__global__ __launch_bounds__(256)
void hist_kernel(const int* __restrict__ dst, int* __restrict__ counts) {
    __shared__ int cnt[NBUCK];
    for (int i = threadIdx.x; i < NBUCK; i += 256) cnt[i] = 0;
    __syncthreads();
    const int base = blockIdx.x * CHUNK;
    const int end = min(base + CHUNK, NE);
    for (int e = base + threadIdx.x; e < end; e += 256)
        atomicAdd(&cnt[dst[e] >> BUCKET_BITS], 1);
    __syncthreads();
    for (int b = threadIdx.x; b < NBUCK; b += 256)
        counts[b * NCHUNKS + blockIdx.x] = cnt[b];
}

// ---------------- generic 3-kernel exclusive scan (multi-block) ----------------
__global__ __launch_bounds__(256)
void block_sums_kernel(const int* __restrict__ v, int* __restrict__ bsums, int n) {
    __shared__ int s[256];
    int i = blockIdx.x * 256 + threadIdx.x;
    s[threadIdx.x] = (i < n) ? v[i] : 0;
    __syncthreads();
    for (int d = 128; d > 0; d >>= 1) {
        if (threadIdx.x < d) s[threadIdx.x] += s[threadIdx.x + d];
        __syncthreads();
    }
    if (threadIdx.x == 0) bsums[blockIdx.x] = s[0];
}

__global__ __launch_bounds__(512)
void scan_bsums_kernel(const int* __restrict__ bsums, int* __restrict__ boff, int nb) {
    __shared__ int s[512];
    int v = (threadIdx.x < nb) ? bsums[threadIdx.x] : 0;
    s[threadIdx.x] = v;
    __syncthreads();
    for (int d = 1; d < 512; d <<= 1) {
        int t = (threadIdx.x >= d) ? s[threadIdx.x - d] : 0;
        __syncthreads();
        s[threadIdx.x] += t;
        __syncthreads();
    }
    if (threadIdx.x < nb) boff[threadIdx.x] = s[threadIdx.x] - v;  // exclusive
}

__global__ __launch_bounds__(256)
void scan_chunks_kernel(const int* __restrict__ v, const int* __restrict__ boff,
                        int* __restrict__ out, int n) {
    __shared__ int s[256];
    int i = blockIdx.x * 256 + threadIdx.x;
    int val = (i < n) ? v[i] : 0;
    s[threadIdx.x] = val;
    __syncthreads();
    for (int d = 1; d < 256; d <<= 1) {
        int t = (threadIdx.x >= d) ? s[threadIdx.x - d] : 0;
        __syncthreads();
        s[threadIdx.x] += t;
        __syncthreads();
    }
    if (i < n) out[i] = boff[blockIdx.x] + s[threadIdx.x] - val;  // exclusive
}

// ---------------- Pass 2: place edges into (bucket,chunk) runs ----------------
// binned payload: .x = src | (dst_local << 17) as bits, .y = weight fp32
__global__ __launch_bounds__(256)
void place_kernel(const int* __restrict__ src, const int* __restrict__ dst,
                  const float* __restrict__ ew, const int* __restrict__ gofs,
                  float2* __restrict__ binned) {
    __shared__ int lcur[NBUCK];
    for (int i = threadIdx.x; i < NBUCK; i += 256) lcur[i] = 0;
    __syncthreads();
    const int base = blockIdx.x * CHUNK;
    const int end = min(base + CHUNK, NE);
    for (int e = base + threadIdx.x; e < end; e += 256) {
        int d = dst[e];
        int b = d >> BUCKET_BITS;
        int p = gofs[b * NCHUNKS + blockIdx.x] + atomicAdd(&lcur[b], 1);
        float2 pk;
        pk.x = __int_as_float(src[e] | ((d & (BNODES - 1)) << 17));
        pk.y = ew[e];
        binned[p] = pk;
    }
}

// ---------------- Pass 3: per-bucket LDS counting sort by (dst_local, src_tile) ----------------
// Output edge record packed to ONE uint: src(17b) | w15(15b, sign-stripped bf16 weight).
__global__ __launch_bounds__(256)
void bucket_sort_kernel(const float2* __restrict__ binned, const int* __restrict__ gofs,
                        unsigned int* __restrict__ edges, int* __restrict__ off) {
    __shared__ unsigned int buf[BUFCAP];
    __shared__ int pos[NKEY];
    __shared__ int psum[256];
    const int tid = threadIdx.x;
    const int b = blockIdx.x;
    const int s = gofs[b * NCHUNKS];
    const int e = (b == NBUCK - 1) ? NE : gofs[(b + 1) * NCHUNKS];
    const int n = e - s;

    for (int i = tid; i < NKEY; i += 256) pos[i] = 0;
    __syncthreads();
    for (int i = tid; i < n; i += 256) {
        int v = __float_as_int(binned[s + i].x);
        int dl = (v >> 17) & (BNODES - 1);
        int t = (v & 0x1FFFF) >> TILE_SHIFT;
        atomicAdd(&pos[(dl << 3) | t], 1);
    }
    __syncthreads();
    constexpr int PER = NKEY / 256;              // 8
    const int base = tid * PER;
    int run = 0;
#pragma unroll
    for (int i = 0; i < PER; ++i) { int c = pos[base + i]; pos[base + i] = run; run += c; }
    psum[tid] = run;
    __syncthreads();
    for (int d = 1; d < 256; d <<= 1) {
        int t = (tid >= d) ? psum[tid - d] : 0;
        __syncthreads();
        psum[tid] += t;
        __syncthreads();
    }
    const int chunk_off = psum[tid] - run;
#pragma unroll
    for (int i = 0; i < PER; ++i) pos[base + i] += chunk_off;
    __syncthreads();
    const int node0 = b * BNODES;
    if (tid < BNODES) {
        int node = node0 + tid;
        if (node < NN) off[node] = s + pos[tid << 3];
    }
    if (b == NBUCK - 1 && tid == 0) off[NN] = NE;
    __syncthreads();
    for (int i = tid; i < n; i += 256) {
        float2 pk = binned[s + i];
        int v = __float_as_int(pk.x);
        int dl = (v >> 17) & (BNODES - 1);
        int t = (v & 0x1FFFF) >> TILE_SHIFT;
        int p = atomicAdd(&pos[(dl << 3) | t], 1);
        unsigned int w15 = (unsigned int)(f2bf(pk.y) & 0x7FFF);  // weight >= 0
        if (p < BUFCAP) buf[p] = (unsigned int)(v & 0x1FFFF) | (w15 << 17);
    }
    __syncthreads();
    const int m = (n < BUFCAP) ? n : BUFCAP;
    for (int i = tid; i < m; i += 256)
        edges[s + i] = buf[i];
}

// ---------------- Aggregation (quarter-wave, free-running) ----------------
// One node per 16-lane quarter-wave; lane loads uint2 = 4 bf16 features (16x8B = full
// 128B row for D=64). 16 nodes per 256-thread block -> 4 gather streams per wave.
// Edge record: src = pk & 0x1FFFF, weight = bf2f(pk >> 17).
template<int D, bool BIAS, bool BF16OUT>
__global__ __launch_bounds__(256)
void agg_kernel(const unsigned short* __restrict__ h, const unsigned int* __restrict__ edges,
                const int* __restrict__ off, uint2* __restrict__ y16,
                float* __restrict__ yf, const float* __restrict__ bias) {
    constexpr int NU = D / 4;                    // uint2 per row
    const uint2* __restrict__ h64 = (const uint2*)h;
    const int fl = threadIdx.x & 15;
    const int v = blockIdx.x * 16 + (threadIdx.x >> 4);
    if (v >= NN) return;
    if (fl >= NU) return;
    const int s = off[v], e = off[v + 1];
    float A0 = 0.f, A1 = 0.f, A2 = 0.f, A3 = 0.f;
    float B0 = 0.f, B1 = 0.f, B2 = 0.f, B3 = 0.f;
    int j = s;
    for (; j + 7 < e; j += 8) {
        unsigned int k0 = edges[j + 0], k1 = edges[j + 1], k2 = edges[j + 2], k3 = edges[j + 3];
        unsigned int k4 = edges[j + 4], k5 = edges[j + 5], k6 = edges[j + 6], k7 = edges[j + 7];
        uint2 g0 = h64[(size_t)(k0 & 0x1FFFF) * NU + fl];
        uint2 g1 = h64[(size_t)(k1 & 0x1FFFF) * NU + fl];
        uint2 g2 = h64[(size_t)(k2 & 0x1FFFF) * NU + fl];
        uint2 g3 = h64[(size_t)(k3 & 0x1FFFF) * NU + fl];
        uint2 g4 = h64[(size_t)(k4 & 0x1FFFF) * NU + fl];
        uint2 g5 = h64[(size_t)(k5 & 0x1FFFF) * NU + fl];
        uint2 g6 = h64[(size_t)(k6 & 0x1FFFF) * NU + fl];
        uint2 g7 = h64[(size_t)(k7 & 0x1FFFF) * NU + fl];
        float w0 = bf2f((unsigned short)(k0 >> 17));
        float w1 = bf2f((unsigned short)(k1 >> 17));
        float w2 = bf2f((unsigned short)(k2 >> 17));
        float w3 = bf2f((unsigned short)(k3 >> 17));
        float w4 = bf2f((unsigned short)(k4 >> 17));
        float w5 = bf2f((unsigned short)(k5 >> 17));
        float w6 = bf2f((unsigned short)(k6 >> 17));
        float w7 = bf2f((unsigned short)(k7 >> 17));
        A0 += bf2f((unsigned short)g0.x) * w0 + bf2f((unsigned short)g1.x) * w1;
        A1 += bf2f((unsigned short)(g0.x >> 16)) * w0 + bf2f((unsigned short)(g1.x >> 16)) * w1;
        A2 += bf2f((unsigned short)g0.y) * w0 + bf2f((unsigned short)g1.y) * w1;
        A3 += bf2f((unsigned short)(g0.y >> 16)) * w0 + bf2f((unsigned short)(g1.y >> 16)) * w1;
        B0 += bf2f((unsigned short)g2.x) * w2 + bf2f((unsigned short)g3.x) * w3;
        B1 += bf2f((unsigned short)(g2.x >> 16)) * w2 + bf2f((unsigned short)(g3.x >> 16)) * w3;
        B2 += bf2f((unsigned short)g2.y) * w2 + bf2f((unsigned short)g3.y) * w3;
        B3 += bf2f((unsigned short)(g2.y >> 16)) * w2 + bf2f((unsigned short)(g3.y >> 16)) * w3;
        A0 += bf2f((unsigned short)g4.x) * w4 + bf2f((unsigned short)g5.x) * w5;
        A1 += bf2f((unsigned short)(g4.x >> 16)) * w4 + bf2f((unsigned short)(g5.x >> 16)) * w5;
        A2 += bf2f((unsigned short)g4.y) * w4 + bf2f((unsigned short)g5.y) * w5;
        A3 += bf2f((unsigned short)(g4.y >> 16)) * w4 + bf2f((unsigned short)(g5.y >> 16)) * w5;
        B0 += bf2f((unsigned short)g6.x) * w6 + bf2f((unsigned short)g7.x) * w7;
        B1 += bf2f((unsigned short)(g6.x >> 16)) * w6 + bf2f((unsigned short)(g7.x >> 16)) * w7;
        B2 += bf2f((unsigned short)g6.y) * w6 + bf2f((unsigned short)g7.y) * w7;
        B3 += bf2f((unsigned short)(g6.y >> 16)) * w6 + bf2f((unsigned short)(g7.y >> 16)) * w7;
    }
    for (; j + 1 < e; j += 2) {
        unsigned int k0 = edges[j], k1 = edges[j + 1];
        uint2 g0 = h64[(size_t)(k0 & 0x1FFFF) * NU + fl];
        uint2 g1 = h64[(size_t)(k1 & 0x1FFFF) * NU + fl];
        float w0 = bf2f((unsigned short)(k0 >> 17));
        float w1 = bf2f((unsigned short)(k1 >> 17));
        A0 += bf2f((unsigned short)g0.x) * w0 + bf2f((unsigned short)g1.x) * w1;
        A1 += bf2f((unsigned short)(g0.x >> 16)) * w0 + bf2f((unsigned short)(g1.x >> 16)) * w1;
        A2 += bf2f((unsigned short)g0.y) * w0 + bf2f((unsigned short)g1.y) * w1;
        A3 += bf2f((unsigned short)(g0.y >> 16)) * w0 + bf2f((unsigned short)(g1.y >> 16)) * w1;
    }
    if (j < e) {
        unsigned int k0 = edges[j];
        uint2 g0 = h64[(size_t)(k0 & 0x1FFFF) * NU + fl];
        float w0 = bf2f((unsigned short)(k0 >> 17));
        B0 += bf2f((unsigned short)g0.x) * w0;
        B1 += bf2f((unsigned short)(g0.x >> 16)) * w0;
        B2 += bf2f((unsigned short)g0.y) * w0;
        B3 += bf2f((unsigned short)(g0.y >> 16)) * w0;
    }
    float r0 = A0 + B0, r1 = A1 + B1, r2 = A2 + B2, r3 = A3 + B3;
    if (BIAS) {
        r0 += bias[4 * fl];     r1 += bias[4 * fl + 1];
        r2 += bias[4 * fl + 2]; r3 += bias[4 * fl + 3];
    }
    if (BF16OUT) {
        uint2 pk;
        pk.x = (unsigned int)f2bf(r0) | ((unsigned int)f2bf(r1) << 16);
        pk.y = (unsigned int)f2bf(r2) | ((unsigned int)f2bf(r3) << 16);
        y16[(size_t)v * NU + fl] = pk;
    } else {
        float4 o = make_float4(r0, r1, r2, r3);
        *(float4*)&yf[(size_t)v * D + 4 * fl] = o;
    }
}

// ---------------- BN stats over bf16 rows: stats[0..63]=sum, stats[64..127]=sumsq ----------------
__global__ __launch_bounds__(256)
void bn_stats_bf16_kernel(const unsigned int* __restrict__ x32, float* __restrict__ stats, int n) {
    __shared__ float s0[256], s1[256], q0[256], q1[256];
    const int tid = threadIdx.x;
    const int fl = tid & 31;
    const int rg = tid >> 5;
    float sum0 = 0.f, sum1 = 0.f, sq0 = 0.f, sq1 = 0.f;
    for (int r = blockIdx.x * 8 + rg; r < n; r += gridDim.x * 8) {
        unsigned int u = x32[(size_t)r * 32 + fl];
        float v0 = bf2f((unsigned short)u);
        float v1 = bf2f((unsigned short)(u >> 16));
        sum0 += v0; sum1 += v1;
        sq0 += v0 * v0; sq1 += v1 * v1;
    }
    s0[tid] = sum0; s1[tid] = sum1; q0[tid] = sq0; q1[tid] = sq1;
    __syncthreads();
    if (tid < 32) {
        float ts0 = 0.f, ts1 = 0.f, tq0 = 0.f, tq1 = 0.f;
#pragma unroll
        for (int k = 0; k < 8; ++k) {
            ts0 += s0[tid + 32 * k]; ts1 += s1[tid + 32 * k];
            tq0 += q0[tid + 32 * k]; tq1 += q1[tid + 32 * k];
        }
        atomicAdd(&stats[2 * tid], ts0);
        atomicAdd(&stats[2 * tid + 1], ts1);
        atomicAdd(&stats[64 + 2 * tid], tq0);
        atomicAdd(&stats[64 + 2 * tid + 1], tq1);
    }
}

extern "C" void kernel_launch(void* const* d_in, const int* in_sizes, int n_in,
                              void* d_out, int out_size, void* d_ws, size_t ws_size,
                              hipStream_t stream) {
    const float* nf    = (const float*)d_in[0];
    const int*   ei    = (const int*)d_in[1];   // [2][E]
    const float* ew    = (const float*)d_in[2];
    const float* W1    = (const float*)d_in[3];
    // b1 (d_in[4]) cancels inside BN
    const float* g1    = (const float*)d_in[5];
    const float* beta1 = (const float*)d_in[6];
    const float* W2    = (const float*)d_in[7];
    // b2 (d_in[8]) cancels inside BN
    const float* g2    = (const float*)d_in[9];
    const float* beta2 = (const float*)d_in[10];
    const float* W3    = (const float*)d_in[11];
    const float* b3    = (const float*)d_in[12];

    const int* src = ei;
    const int* dst = ei + NE;

    // workspace layout (4B units)
    unsigned short* hbuf = (unsigned short*)d_ws;        // NN*64 bf16 (12.8MB); binned aliases it
    unsigned short* abuf = hbuf + (size_t)NN * 64;       // NN*64 bf16 (agg output)
    float2* binned = (float2*)(abuf + (size_t)NN * 64);  // NE float2 (sort scratch)
    unsigned int* edges = (unsigned int*)(binned + NE);  // NE uint (packed CSR)
    int*    off    = (int*)(edges + NE);                 // NN+1
    int*    counts = off + NN + 1;                       // SCAN_N
    int*    gofs   = counts + SCAN_N;                    // SCAN_N
    int*    bsums  = gofs + SCAN_N;                      // 512
    int*    boff   = bsums + 512;                        // 512
    float*  stats1 = (float*)(boff + 512);               // 128
    float*  stats2 = stats1 + 128;                       // 128

    float* out = (float*)d_out;

    const int SB = (SCAN_N + 255) / 256;   // 391
    const int ggrid = (NN + 63) / 64;      // 1563
    const int agrid = (NN + 15) / 16;      // 6250

    // ---------- zero stats banks ----------
    (void)hipMemsetAsync(stats1, 0, 256 * sizeof(float), stream);

    // ---------- CSR build: hist -> 3-kernel scan -> place -> bucket sort ----------
    hist_kernel<<<NCHUNKS, 256, 0, stream>>>(dst, counts);
    block_sums_kernel<<<SB, 256, 0, stream>>>(counts, bsums, SCAN_N);
    scan_bsums_kernel<<<1, 512, 0, stream>>>(bsums, boff, SB);
    scan_chunks_kernel<<<SB, 256, 0, stream>>>(counts, boff, gofs, SCAN_N);
    place_kernel<<<NCHUNKS, 256, 0, stream>>>(src, dst, ew, gofs, binned);
    bucket_sort_kernel<<<NBUCK, 256, 0, stream>>>(binned, gofs, edges, off);

    // ---------- layer 1: GCNConv(128->64); agg -> bf16; stats1 ----------
    gemm_mfma_kernel<128, 64, 4, false, false><<<ggrid, 256, 0, stream>>>(
        nf, W1, hbuf, NN, nullptr, nullptr, nullptr);
    agg_kernel<64, false, true><<<agrid, 256, 0, stream>>>(
        hbuf, edges, off, (uint2*)abuf, nullptr, nullptr);
    bn_stats_bf16_kernel<<<512, 256, 0, stream>>>((const unsigned int*)abuf, stats1, NN);

    // ---------- layer 2: BN1+ReLU fused in GEMM; agg -> bf16; stats2 ----------
    gemm_mfma_kernel<64, 64, 4, true, true><<<ggrid, 256, 0, stream>>>(
        abuf, W2, hbuf, NN, stats1, g1, beta1);
    agg_kernel<64, false, true><<<agrid, 256, 0, stream>>>(
        hbuf, edges, off, (uint2*)abuf, nullptr, nullptr);
    bn_stats_bf16_kernel<<<512, 256, 0, stream>>>((const unsigned int*)abuf, stats2, NN);

    // ---------- layer 3: BN2+ReLU fused in GEMM; agg + b3 -> out (fp32) ----------
    gemm_mfma_kernel<64, 40, 3, true, true><<<ggrid, 256, 0, stream>>>(
        abuf, W3, hbuf, NN, stats2, g2, beta2);
    agg_kernel<40, true, false><<<agrid, 256, 0, stream>>>(
        hbuf, edges, off, nullptr, out, b3);
}